// Round 4
// baseline (41.355 us; speedup 1.0000x reference)
//
#include <hip/hip_runtime.h>
#include <stdint.h>

#define NCFG 96
#define GROUPS 8
#define CELL_BLOCKS 250          // 64000 / 256

namespace ct {

// ---------------- compile-time numpy RandomState(0) replica ----------------
struct Tabs {
  int topo2tri[NCFG];
  int e0[NCFG][4];
  int e1[NCFG][4];
  int e2[NCFG][4];
  int ntri[NCFG];
  int nactive;          // # configs with ntri >= 2 (others contribute 0)
  int aorder[NCFG];     // active configs sorted by topo column (stable)
};

struct MT {
  uint32_t mt[624];
  int pos;
  constexpr MT() : mt{}, pos(624) {
    uint32_t s = 0u;                      // mt19937 init_genrand(0)
    for (int i = 0; i < 624; ++i) {
      mt[i] = s;
      s = 1812433253u * (s ^ (s >> 30)) + (uint32_t)(i + 1);
    }
  }
  constexpr uint32_t next() {
    if (pos >= 624) {
      for (int i = 0; i < 624; ++i) {
        uint32_t y = (mt[i] & 0x80000000u) |
                     (mt[(i + 1) == 624 ? 0 : (i + 1)] & 0x7fffffffu);
        uint32_t v = mt[(i + 397) >= 624 ? (i + 397 - 624) : (i + 397)] ^ (y >> 1);
        if (y & 1u) v ^= 0x9908b0dfu;
        mt[i] = v;
      }
      pos = 0;
    }
    uint32_t y = mt[pos++];
    y ^= y >> 11;
    y ^= (y << 7) & 0x9d2c5680u;
    y ^= (y << 15) & 0xefc60000u;
    y ^= y >> 18;
    return y;
  }
};

constexpr Tabs make_tabs() {
  Tabs t{};
  MT g{};
  // TOPO2TRI = randint(0, 256, 96): masked draw, mask=255, never rejects
  for (int i = 0; i < NCFG; ++i) t.topo2tri[i] = (int)(g.next() & 255u);
  // TRI_EDGES = rand(96,4,12).argsort(-1)[..., :3]
  // rk_double = (a*2^26+b)/2^53 ; key=(a<<26)|b is order-isomorphic
  for (int c = 0; c < NCFG; ++c) {
    for (int tr = 0; tr < 4; ++tr) {
      uint64_t key[12] = {};
      for (int k = 0; k < 12; ++k) {
        uint64_t a = (uint64_t)(g.next() >> 5);
        uint64_t b = (uint64_t)(g.next() >> 6);
        key[k] = (a << 26) | b;
      }
      bool used[12] = {};
      int sel[3] = {};
      for (int s = 0; s < 3; ++s) {
        int best = -1;
        for (int k = 0; k < 12; ++k)
          if (!used[k] && (best < 0 || key[k] < key[best])) best = k;
        used[best] = true;
        sel[s] = best;
      }
      t.e0[c][tr] = sel[0];
      t.e1[c][tr] = sel[1];
      t.e2[c][tr] = sel[2];
    }
  }
  // _NTRI = randint(1, 5, 96): 1 + (draw & 3), never rejects
  for (int c = 0; c < NCFG; ++c) t.ntri[c] = 1 + (int)(g.next() & 3u);
  // active configs only, stable-sorted by column (slot dedup + L1 locality)
  int na = 0;
  for (int i = 0; i < NCFG; ++i)
    if (t.ntri[i] > 1) t.aorder[na++] = i;
  t.nactive = na;
  for (int i = 1; i < na; ++i) {
    int v = t.aorder[i];
    int j = i - 1;
    while (j >= 0 && t.topo2tri[t.aorder[j]] > t.topo2tri[v]) {
      t.aorder[j + 1] = t.aorder[j];
      --j;
    }
    t.aorder[j + 1] = v;
  }
  return t;
}

constexpr Tabs TAB = make_tabs();

// EDGES = [(dx,dy,dz,ax) x 12]
constexpr int EDX[12] = {0,0,0,0, 0,1,0,1, 0,1,0,1};
constexpr int EDY[12] = {0,1,0,1, 0,0,0,0, 0,0,1,1};
constexpr int EDZ[12] = {0,0,1,1, 0,0,1,1, 0,0,0,0};
constexpr int EAX[12] = {0,0,0,0, 1,1,1,1, 2,2,2,2};

constexpr int NA = TAB.nactive;
constexpr int PG = (NA + GROUPS - 1) / GROUPS;
constexpr int gstart(int g) { int s = g * PG; return s > NA ? NA : s; }
constexpr int gend(int g)   { int e = (g + 1) * PG; return e > NA ? NA : e; }

} // namespace ct

// ---------------- device math, fully unrolled via templates ----------------

template<int C, int T>
__device__ __forceinline__ void tri_nq(const float (&o)[12], float (&n)[3], float& q) {
  constexpr int ea = ct::TAB.e0[C][T];
  constexpr int eb = ct::TAB.e1[C][T];
  constexpr int ec = ct::TAB.e2[C][T];
  // cell base cancels in vertex differences: corner diffs + off terms remain
  float d1[3] = { (float)(ct::EDX[eb] - ct::EDX[ea]),
                  (float)(ct::EDY[eb] - ct::EDY[ea]),
                  (float)(ct::EDZ[eb] - ct::EDZ[ea]) };
  float d2[3] = { (float)(ct::EDX[ec] - ct::EDX[ea]),
                  (float)(ct::EDY[ec] - ct::EDY[ea]),
                  (float)(ct::EDZ[ec] - ct::EDZ[ea]) };
  d1[ct::EAX[eb]] += o[eb];
  d1[ct::EAX[ea]] -= o[ea];
  d2[ct::EAX[ec]] += o[ec];
  d2[ct::EAX[ea]] -= o[ea];
  n[0] = d1[1] * d2[2] - d1[2] * d2[1];
  n[1] = d1[2] * d2[0] - d1[0] * d2[2];
  n[2] = d1[0] * d2[1] - d1[1] * d2[0];
  q = n[0]*n[0] + n[1]*n[1] + n[2]*n[2];
}

// 1 - cos(angle): one rsq per pair instead of 2 sqrt + 1 rcp
// (drops ref's +1e-8 on the norms: ~1e-8 relative, threshold is ~2% of output)
__device__ __forceinline__ float pair_term(const float (&a)[3], float qa,
                                           const float (&b)[3], float qb) {
  float d = a[0]*b[0] + a[1]*b[1] + a[2]*b[2];
  return 1.0f - d * __builtin_amdgcn_rsqf(qa * qb);
}

template<int C>
__device__ __forceinline__ float config_curv(const float (&o)[12]) {
  constexpr int NT = ct::TAB.ntri[C];   // >= 2 when called
  float n0[3], n1[3], n2[3], n3[3];
  float q0 = 0.f, q1 = 0.f, q2 = 0.f, q3 = 0.f;
  tri_nq<C, 0>(o, n0, q0);
  tri_nq<C, 1>(o, n1, q1);
  if constexpr (NT > 2) tri_nq<C, 2>(o, n2, q2);
  if constexpr (NT > 3) tri_nq<C, 3>(o, n3, q3);
  float curv = pair_term(n0, q0, n1, q1);
  if constexpr (NT > 2) curv += pair_term(n1, q1, n2, q2);
  if constexpr (NT > 3) curv += pair_term(n2, q2, n3, q3);
  return curv;
}

template<int K>
__device__ __forceinline__ float f4get(const float4& v) {
  if constexpr (K == 0) return v.x;
  else if constexpr (K == 1) return v.y;
  else if constexpr (K == 2) return v.z;
  else return v.w;
}

// Walk sorted active configs [I, END). Carry a running curv sum across configs
// sharing the same topo column (one FMA per column run), and reuse the
// current float4 slot (LOADED = slot id in slotv, -1 = none) so each 16B
// topo slot is loaded at most once per thread.
template<int I, int END, bool RUN, int LOADED>
__device__ __forceinline__ void do_act(const float (&o)[12],
                                       const float4* __restrict__ topoRow4,
                                       float& acc, float carry, float4& slotv) {
  if constexpr (I < END) {
    constexpr int c   = ct::TAB.aorder[I];
    constexpr int col = ct::TAB.topo2tri[c];
    float nc = carry + config_curv<c>(o);
    constexpr bool flush = (I + 1 == END) ||
        (ct::TAB.topo2tri[ct::TAB.aorder[(I + 1 < END) ? I + 1 : I]] != col);
    if constexpr (flush) {
      constexpr int slot = col >> 2;
      if constexpr (LOADED != slot) slotv = topoRow4[slot];
      acc += f4get<(col & 3)>(slotv) * nc;
      do_act<I + 1, END, false, slot>(o, topoRow4, acc, 0.0f, slotv);
    } else {
      do_act<I + 1, END, true, LOADED>(o, topoRow4, acc, nc, slotv);
    }
  }
}

__global__ __launch_bounds__(256)
void curv_kernel(const float* __restrict__ off, const float* __restrict__ topo,
                 float* __restrict__ out) {
  const int cb = blockIdx.x % CELL_BLOCKS;
  const int g  = blockIdx.x / CELL_BLOCKS;
  const int cell = cb * 256 + (int)threadIdx.x;
  const int x = cell / 1600;
  const int r = cell - x * 1600;
  const int y = r / 40;
  const int z = r - y * 40;

  // 12 per-cell edge offsets; coalesced (consecutive lanes = consecutive z)
  float o[12];
#pragma unroll
  for (int e = 0; e < 12; ++e) {
    o[e] = off[ct::EAX[e] * 68921 + (x + ct::EDX[e]) * 1681 +
               (y + ct::EDY[e]) * 41 + (z + ct::EDZ[e])];
  }

  const float4* topoRow4 = (const float4*)(topo + (size_t)cell * 256);
  float acc = 0.0f;
  float4 slotv;
  switch (g) {
    case 0: do_act<ct::gstart(0), ct::gend(0), false, -1>(o, topoRow4, acc, 0.0f, slotv); break;
    case 1: do_act<ct::gstart(1), ct::gend(1), false, -1>(o, topoRow4, acc, 0.0f, slotv); break;
    case 2: do_act<ct::gstart(2), ct::gend(2), false, -1>(o, topoRow4, acc, 0.0f, slotv); break;
    case 3: do_act<ct::gstart(3), ct::gend(3), false, -1>(o, topoRow4, acc, 0.0f, slotv); break;
    case 4: do_act<ct::gstart(4), ct::gend(4), false, -1>(o, topoRow4, acc, 0.0f, slotv); break;
    case 5: do_act<ct::gstart(5), ct::gend(5), false, -1>(o, topoRow4, acc, 0.0f, slotv); break;
    case 6: do_act<ct::gstart(6), ct::gend(6), false, -1>(o, topoRow4, acc, 0.0f, slotv); break;
    default: do_act<ct::gstart(7), ct::gend(7), false, -1>(o, topoRow4, acc, 0.0f, slotv); break;
  }

  // wave reduce (64 lanes), then 4 waves, then one atomic per block
#pragma unroll
  for (int d = 32; d > 0; d >>= 1) acc += __shfl_down(acc, d, 64);
  __shared__ float wsum[4];
  const int lane = threadIdx.x & 63;
  const int w = threadIdx.x >> 6;
  if (lane == 0) wsum[w] = acc;
  __syncthreads();
  if (threadIdx.x == 0)
    atomicAdd(out, wsum[0] + wsum[1] + wsum[2] + wsum[3]);
}

extern "C" void kernel_launch(void* const* d_in, const int* in_sizes, int n_in,
                              void* d_out, int out_size, void* d_ws, size_t ws_size,
                              hipStream_t stream) {
  const float* off  = (const float*)d_in[0];   // [3, 41, 41, 41] f32
  const float* topo = (const float*)d_in[1];   // [64000, 256] f32
  float* out = (float*)d_out;                  // scalar f32

  hipMemsetAsync(out, 0, sizeof(float), stream);
  curv_kernel<<<dim3(CELL_BLOCKS * GROUPS), dim3(256), 0, stream>>>(off, topo, out);
}

// Round 5
// 19.578 us; speedup vs baseline: 2.1124x; 2.1124x over previous
//
#include <hip/hip_runtime.h>
#include <stdint.h>

#define NCFG 96
#define CELL_BLOCKS 250          // 64000 / 256
#define NPART CELL_BLOCKS

namespace ct {

// ---------------- compile-time numpy RandomState(0) replica ----------------
struct Tabs {
  int topo2tri[NCFG];
  int e0[NCFG][4];
  int e1[NCFG][4];
  int e2[NCFG][4];
  int ntri[NCFG];
  int nactive;          // # configs with ntri >= 2 (others contribute 0)
  int aorder[NCFG];     // active configs sorted by topo column (stable)
};

struct MT {
  uint32_t mt[624];
  int pos;
  constexpr MT() : mt{}, pos(624) {
    uint32_t s = 0u;                      // mt19937 init_genrand(0)
    for (int i = 0; i < 624; ++i) {
      mt[i] = s;
      s = 1812433253u * (s ^ (s >> 30)) + (uint32_t)(i + 1);
    }
  }
  constexpr uint32_t next() {
    if (pos >= 624) {
      for (int i = 0; i < 624; ++i) {
        uint32_t y = (mt[i] & 0x80000000u) |
                     (mt[(i + 1) == 624 ? 0 : (i + 1)] & 0x7fffffffu);
        uint32_t v = mt[(i + 397) >= 624 ? (i + 397 - 624) : (i + 397)] ^ (y >> 1);
        if (y & 1u) v ^= 0x9908b0dfu;
        mt[i] = v;
      }
      pos = 0;
    }
    uint32_t y = mt[pos++];
    y ^= y >> 11;
    y ^= (y << 7) & 0x9d2c5680u;
    y ^= (y << 15) & 0xefc60000u;
    y ^= y >> 18;
    return y;
  }
};

constexpr Tabs make_tabs() {
  Tabs t{};
  MT g{};
  // TOPO2TRI = randint(0, 256, 96): masked draw, mask=255, never rejects
  for (int i = 0; i < NCFG; ++i) t.topo2tri[i] = (int)(g.next() & 255u);
  // TRI_EDGES = rand(96,4,12).argsort(-1)[..., :3]
  // rk_double = (a*2^26+b)/2^53 ; key=(a<<26)|b is order-isomorphic
  for (int c = 0; c < NCFG; ++c) {
    for (int tr = 0; tr < 4; ++tr) {
      uint64_t key[12] = {};
      for (int k = 0; k < 12; ++k) {
        uint64_t a = (uint64_t)(g.next() >> 5);
        uint64_t b = (uint64_t)(g.next() >> 6);
        key[k] = (a << 26) | b;
      }
      bool used[12] = {};
      int sel[3] = {};
      for (int s = 0; s < 3; ++s) {
        int best = -1;
        for (int k = 0; k < 12; ++k)
          if (!used[k] && (best < 0 || key[k] < key[best])) best = k;
        used[best] = true;
        sel[s] = best;
      }
      t.e0[c][tr] = sel[0];
      t.e1[c][tr] = sel[1];
      t.e2[c][tr] = sel[2];
    }
  }
  // _NTRI = randint(1, 5, 96): 1 + (draw & 3), never rejects
  for (int c = 0; c < NCFG; ++c) t.ntri[c] = 1 + (int)(g.next() & 3u);
  // active configs only, stable-sorted by column (load dedup + L1 locality)
  int na = 0;
  for (int i = 0; i < NCFG; ++i)
    if (t.ntri[i] > 1) t.aorder[na++] = i;
  t.nactive = na;
  for (int i = 1; i < na; ++i) {
    int v = t.aorder[i];
    int j = i - 1;
    while (j >= 0 && t.topo2tri[t.aorder[j]] > t.topo2tri[v]) {
      t.aorder[j + 1] = t.aorder[j];
      --j;
    }
    t.aorder[j + 1] = v;
  }
  return t;
}

constexpr Tabs TAB = make_tabs();

// EDGES = [(dx,dy,dz,ax) x 12]
constexpr int EDX[12] = {0,0,0,0, 0,1,0,1, 0,1,0,1};
constexpr int EDY[12] = {0,1,0,1, 0,0,0,0, 0,0,1,1};
constexpr int EDZ[12] = {0,0,1,1, 0,0,1,1, 0,0,0,0};
constexpr int EAX[12] = {0,0,0,0, 1,1,1,1, 2,2,2,2};

constexpr int NA = TAB.nactive;

} // namespace ct

// ---------------- device math, fully unrolled via templates ----------------

template<int C, int T>
__device__ __forceinline__ void tri_nq(const float (&o)[12], float (&n)[3], float& q) {
  constexpr int ea = ct::TAB.e0[C][T];
  constexpr int eb = ct::TAB.e1[C][T];
  constexpr int ec = ct::TAB.e2[C][T];
  // cell base cancels in vertex differences: corner diffs + off terms remain
  float d1[3] = { (float)(ct::EDX[eb] - ct::EDX[ea]),
                  (float)(ct::EDY[eb] - ct::EDY[ea]),
                  (float)(ct::EDZ[eb] - ct::EDZ[ea]) };
  float d2[3] = { (float)(ct::EDX[ec] - ct::EDX[ea]),
                  (float)(ct::EDY[ec] - ct::EDY[ea]),
                  (float)(ct::EDZ[ec] - ct::EDZ[ea]) };
  d1[ct::EAX[eb]] += o[eb];
  d1[ct::EAX[ea]] -= o[ea];
  d2[ct::EAX[ec]] += o[ec];
  d2[ct::EAX[ea]] -= o[ea];
  n[0] = d1[1] * d2[2] - d1[2] * d2[1];
  n[1] = d1[2] * d2[0] - d1[0] * d2[2];
  n[2] = d1[0] * d2[1] - d1[1] * d2[0];
  q = n[0]*n[0] + n[1]*n[1] + n[2]*n[2];
}

// 1 - cos(angle): one rsq per pair instead of 2 sqrt + 1 rcp
// (drops ref's +1e-8 on the norms: ~1e-8 relative, threshold is ~2% of output)
__device__ __forceinline__ float pair_term(const float (&a)[3], float qa,
                                           const float (&b)[3], float qb) {
  float d = a[0]*b[0] + a[1]*b[1] + a[2]*b[2];
  return 1.0f - d * __builtin_amdgcn_rsqf(qa * qb);
}

template<int C>
__device__ __forceinline__ float config_curv(const float (&o)[12]) {
  constexpr int NT = ct::TAB.ntri[C];   // >= 2 when called
  float n0[3], n1[3], n2[3], n3[3];
  float q0 = 0.f, q1 = 0.f, q2 = 0.f, q3 = 0.f;
  tri_nq<C, 0>(o, n0, q0);
  tri_nq<C, 1>(o, n1, q1);
  if constexpr (NT > 2) tri_nq<C, 2>(o, n2, q2);
  if constexpr (NT > 3) tri_nq<C, 3>(o, n3, q3);
  float curv = pair_term(n0, q0, n1, q1);
  if constexpr (NT > 2) curv += pair_term(n1, q1, n2, q2);
  if constexpr (NT > 3) curv += pair_term(n2, q2, n3, q3);
  return curv;
}

// Walk ALL sorted active configs [I, END). Carry a running curv sum across
// configs sharing the same topo column; one INDEPENDENT scalar topo load +
// one FMA per distinct column (loads carry no register dependency on each
// other -> full memory-level parallelism, unlike the R4 slot chain).
template<int I, int END>
__device__ __forceinline__ void do_act(const float (&o)[12],
                                       const float* __restrict__ topoRow,
                                       float& acc, float carry) {
  if constexpr (I < END) {
    constexpr int c   = ct::TAB.aorder[I];
    constexpr int col = ct::TAB.topo2tri[c];
    float nc = carry + config_curv<c>(o);
    constexpr bool flush = (I + 1 == END) ||
        (ct::TAB.topo2tri[ct::TAB.aorder[(I + 1 < END) ? I + 1 : I]] != col);
    if constexpr (flush) {
      acc += topoRow[col] * nc;
      do_act<I + 1, END>(o, topoRow, acc, 0.0f);
    } else {
      do_act<I + 1, END>(o, topoRow, acc, nc);
    }
  }
}

// One thread = one cell, ALL configs. Block footprint in topo is 256 KB
// CONTIGUOUS (rows cb*256 .. cb*256+255), every 64B line fetched exactly
// once chip-wide -> DRAM-stream-friendly, no cross-group L3 amplification.
__global__ __launch_bounds__(256, 1)
void curv_kernel(const float* __restrict__ off, const float* __restrict__ topo,
                 float* __restrict__ partials) {
  const int cell = blockIdx.x * 256 + (int)threadIdx.x;
  const int x = cell / 1600;
  const int r = cell - x * 1600;
  const int y = r / 40;
  const int z = r - y * 40;

  // 12 per-cell edge offsets; coalesced (consecutive lanes = consecutive z)
  float o[12];
#pragma unroll
  for (int e = 0; e < 12; ++e) {
    o[e] = off[ct::EAX[e] * 68921 + (x + ct::EDX[e]) * 1681 +
               (y + ct::EDY[e]) * 41 + (z + ct::EDZ[e])];
  }

  const float* topoRow = topo + (size_t)cell * 256;
  float acc = 0.0f;
  do_act<0, ct::NA>(o, topoRow, acc, 0.0f);

  // wave reduce (64 lanes), then 4 waves -> one partial per block
#pragma unroll
  for (int d = 32; d > 0; d >>= 1) acc += __shfl_down(acc, d, 64);
  __shared__ float wsum[4];
  const int lane = threadIdx.x & 63;
  const int w = threadIdx.x >> 6;
  if (lane == 0) wsum[w] = acc;
  __syncthreads();
  if (threadIdx.x == 0)
    partials[blockIdx.x] = wsum[0] + wsum[1] + wsum[2] + wsum[3];
}

__global__ __launch_bounds__(256)
void reduce_kernel(const float* __restrict__ partials, float* __restrict__ out) {
  float s = 0.0f;
  for (int i = threadIdx.x; i < NPART; i += 256) s += partials[i];
#pragma unroll
  for (int d = 32; d > 0; d >>= 1) s += __shfl_down(s, d, 64);
  __shared__ float wsum[4];
  const int lane = threadIdx.x & 63;
  const int w = threadIdx.x >> 6;
  if (lane == 0) wsum[w] = s;
  __syncthreads();
  if (threadIdx.x == 0) out[0] = wsum[0] + wsum[1] + wsum[2] + wsum[3];
}

extern "C" void kernel_launch(void* const* d_in, const int* in_sizes, int n_in,
                              void* d_out, int out_size, void* d_ws, size_t ws_size,
                              hipStream_t stream) {
  const float* off  = (const float*)d_in[0];   // [3, 41, 41, 41] f32
  const float* topo = (const float*)d_in[1];   // [64000, 256] f32
  float* out = (float*)d_out;                  // scalar f32
  float* partials = (float*)d_ws;              // NPART floats

  curv_kernel<<<dim3(CELL_BLOCKS), dim3(256), 0, stream>>>(off, topo, partials);
  reduce_kernel<<<dim3(1), dim3(256), 0, stream>>>(partials, out);
}